// Round 1
// baseline (77.574 us; speedup 1.0000x reference)
//
#include <hip/hip_runtime.h>

#define NC    129          // lags 0..128
#define LLEN  8192
#define COM   (LLEN - 128) // 8064
#define KTILE 16
#define NKT   9            // ceil(129/16)
#define BB    32

// Kernel 1: raw lag sums S[sig][b][k] = sum_t (x[t]-mu) * x[t+k], t in [0,8064)
__global__ __launch_bounds__(256) void ac_sums_kernel(const float* __restrict__ fake,
                                                      const float* __restrict__ real,
                                                      float* __restrict__ S) {
    __shared__ float sx[8256];     // 8192 row + 64 zero pad (window overreads to 8207)
    __shared__ float sred[64];

    const int tid   = threadIdx.x;
    const int ktile = blockIdx.x;
    const int b     = blockIdx.y;
    const int sig   = blockIdx.z;
    const float* x  = (sig == 0 ? fake : real) + (size_t)b * LLEN;

    // ---- stage full row into LDS (float4), accumulate sum of x[0:8064] ----
    float psum = 0.f;
#pragma unroll
    for (int i = 0; i < 8; ++i) {
        int g = tid + 256 * i;                       // float4 index 0..2047
        float4 v = reinterpret_cast<const float4*>(x)[g];
        reinterpret_cast<float4*>(sx)[g] = v;
        if (g < COM / 4) psum += (v.x + v.y) + (v.z + v.w);
    }
    if (tid < 64) sx[8192 + tid] = 0.f;              // zero the pad

    // wave butterfly (64 lanes) + cross-wave reduce for the mean
    for (int off = 1; off < 64; off <<= 1) psum += __shfl_xor(psum, off);
    if ((tid & 63) == 0) sred[tid >> 6] = psum;
    __syncthreads();
    const float mu = (sred[0] + sred[1] + sred[2] + sred[3]) * (1.0f / COM);

    // ---- sliding-window correlation: 16 lags per block ----
    const int k0 = ktile * KTILE;                    // 4-aligned
    float acc[KTILE];
#pragma unroll
    for (int k = 0; k < KTILE; ++k) acc[k] = 0.f;

    for (int i = 0; i < 8; ++i) {
        int g = tid + 256 * i;                       // float4 group of t
        if (g < COM / 4) {
            float4 x0 = reinterpret_cast<const float4*>(sx)[g];
            const float c0 = x0.x - mu, c1 = x0.y - mu, c2 = x0.z - mu, c3 = x0.w - mu;
            float w[20];
            const int base = 4 * g + k0;             // 4-aligned float index
#pragma unroll
            for (int j = 0; j < 5; ++j) {
                float4 wv = *reinterpret_cast<const float4*>(&sx[base + 4 * j]);
                w[4 * j + 0] = wv.x; w[4 * j + 1] = wv.y;
                w[4 * j + 2] = wv.z; w[4 * j + 3] = wv.w;
            }
#pragma unroll
            for (int k = 0; k < KTILE; ++k) {
                acc[k] = fmaf(c0, w[k + 0], acc[k]);
                acc[k] = fmaf(c1, w[k + 1], acc[k]);
                acc[k] = fmaf(c2, w[k + 2], acc[k]);
                acc[k] = fmaf(c3, w[k + 3], acc[k]);
            }
        }
    }

    // ---- reduce each lag across the block ----
#pragma unroll
    for (int k = 0; k < KTILE; ++k)
        for (int off = 1; off < 64; off <<= 1) acc[k] += __shfl_xor(acc[k], off);

    __syncthreads();                                  // sred reuse
    const int wave = tid >> 6, lane = tid & 63;
    if (lane == 0) {
#pragma unroll
        for (int k = 0; k < KTILE; ++k) sred[wave * KTILE + k] = acc[k];
    }
    __syncthreads();
    if (tid < KTILE) {
        int gk = k0 + tid;
        if (gk < NC) {
            float s = sred[tid] + sred[KTILE + tid] + sred[2 * KTILE + tid] + sred[3 * KTILE + tid];
            S[((size_t)sig * BB + b) * NC + gk] = s;
        }
    }
}

// Kernel 2: out = mean_{b,k} | Sf[b,k]/Sf[b,0] - Sr[b,k]/Sr[b,0] |
__global__ __launch_bounds__(256) void loss_kernel(const float* __restrict__ S,
                                                   float* __restrict__ out) {
    __shared__ float sred[4];
    const float* Sf = S;
    const float* Sr = S + (size_t)BB * NC;
    const int tid = threadIdx.x;

    float a = 0.f;
    for (int idx = tid; idx < BB * NC; idx += 256) {
        int b = idx / NC;
        int k = idx - b * NC;
        float fr = Sf[b * NC + k] / Sf[b * NC];
        float rr = Sr[b * NC + k] / Sr[b * NC];
        a += fabsf(fr - rr);
    }
    for (int off = 1; off < 64; off <<= 1) a += __shfl_xor(a, off);
    if ((tid & 63) == 0) sred[tid >> 6] = a;
    __syncthreads();
    if (tid == 0) out[0] = (sred[0] + sred[1] + sred[2] + sred[3]) * (1.0f / (BB * NC));
}

extern "C" void kernel_launch(void* const* d_in, const int* in_sizes, int n_in,
                              void* d_out, int out_size, void* d_ws, size_t ws_size,
                              hipStream_t stream) {
    const float* fake = (const float*)d_in[0];
    const float* real = (const float*)d_in[1];
    float* S = (float*)d_ws;                      // 2*32*129*4 = 33024 bytes
    float* out = (float*)d_out;

    dim3 grid(NKT, BB, 2);
    ac_sums_kernel<<<grid, 256, 0, stream>>>(fake, real, S);
    loss_kernel<<<1, 256, 0, stream>>>(S, out);
}